// Round 5
// baseline (419.501 us; speedup 1.0000x reference)
//
#include <hip/hip_runtime.h>

typedef short  bf16x8 __attribute__((ext_vector_type(8)));
typedef float  f32x4  __attribute__((ext_vector_type(4)));

__device__ __forceinline__ unsigned short f2bf(float x) {
    unsigned int u = __float_as_uint(x);
    u += 0x7FFFu + ((u >> 16) & 1u);   // round-to-nearest-even
    return (unsigned short)(u >> 16);
}
__device__ __forceinline__ unsigned int pack2(float lo, float hi) {
    return (unsigned int)f2bf(lo) | ((unsigned int)f2bf(hi) << 16);
}

// ---------------- bf16 MFMA GEMM, 128x128 tile, K=256 -------------------------
// A: bf16, rows at stride lda shorts (padded arena, no row guard on loads).
// Bt: bf16 [*][256] (B transposed). C: bf16 (ldc,coff) or fp32 (guarded, ldc,coff).
// EPI: 0=none, 2=+bias, 3=relu(+bias) for gn<256 only (fused MLP1|conv1 weights).
// SWZ: 1D grid, groups of 32 blocks = 8 mtiles x 4 ntiles, id%8==mtile%8 so all
// 4 ntiles of an mtile land on one XCD -> A strip L2-resident (3.2 MB/XCD).
template<bool OUT_BF16, int EPI, bool SWZ>
__global__ __launch_bounds__(256)
void gemm_mfma(const unsigned short* __restrict__ A,
               const unsigned short* __restrict__ Bt,
               const float* __restrict__ bias, void* __restrict__ Cout,
               int M, int mT, int lda, int ldc, int coff)
{
    constexpr int K = 256, BK = 32, ROWP = 40;  // 80B LDS row stride: 0 bank conflicts (measured R3/R4)
    __shared__ unsigned short As[128 * ROWP];
    __shared__ unsigned short Bs[128 * ROWP];

    int mtile, ntile;
    if (SWZ) {
        const int g = blockIdx.x >> 5, w = blockIdx.x & 31;
        mtile = g * 8 + (w & 7);
        ntile = w >> 3;
        if (mtile >= mT) return;
    } else {
        mtile = blockIdx.x;
        ntile = blockIdx.y;
    }
    const int mBase = mtile * 128, nBase = ntile * 128;

    const int tid = threadIdx.x;
    const int lane = tid & 63, wid = tid >> 6;
    const int wm = wid & 1, wn = wid >> 1;      // 2x2 waves, each 64x64
    const int l15 = lane & 15, lq = lane >> 4;

    f32x4 acc[4][4];
#pragma unroll
    for (int mt = 0; mt < 4; ++mt)
#pragma unroll
        for (int nt = 0; nt < 4; ++nt)
            acc[mt][nt] = (f32x4){0.f, 0.f, 0.f, 0.f};

    const int srow = tid >> 1;          // 0..127
    const int sseg = (tid & 1) * 16;    // 0 / 16 shorts

    for (int k0 = 0; k0 < K; k0 += BK) {
        {
            const uint4* p = (const uint4*)&A[(size_t)(mBase + srow) * lda + k0 + sseg];
            *(uint4*)&As[srow * ROWP + sseg]     = p[0];
            *(uint4*)&As[srow * ROWP + sseg + 8] = p[1];
            const uint4* q = (const uint4*)&Bt[(size_t)(nBase + srow) * 256 + k0 + sseg];
            *(uint4*)&Bs[srow * ROWP + sseg]     = q[0];
            *(uint4*)&Bs[srow * ROWP + sseg + 8] = q[1];
        }
        __syncthreads();

        bf16x8 af[4], bfr[4];
#pragma unroll
        for (int mt = 0; mt < 4; ++mt)
            af[mt] = *(const bf16x8*)&As[(wm * 64 + mt * 16 + l15) * ROWP + lq * 8];
#pragma unroll
        for (int nt = 0; nt < 4; ++nt)
            bfr[nt] = *(const bf16x8*)&Bs[(wn * 64 + nt * 16 + l15) * ROWP + lq * 8];
#pragma unroll
        for (int mt = 0; mt < 4; ++mt)
#pragma unroll
            for (int nt = 0; nt < 4; ++nt)
                acc[mt][nt] = __builtin_amdgcn_mfma_f32_16x16x32_bf16(
                    af[mt], bfr[nt], acc[mt][nt], 0, 0, 0);
        __syncthreads();
    }

#pragma unroll
    for (int mt = 0; mt < 4; ++mt) {
#pragma unroll
        for (int nt = 0; nt < 4; ++nt) {
            const int gn = nBase + wn * 64 + nt * 16 + l15;
#pragma unroll
            for (int i = 0; i < 4; ++i) {
                const int gm = mBase + wm * 64 + mt * 16 + lq * 4 + i;
                float v = acc[mt][nt][i];
                if (EPI == 2) v += bias[gn];
                if (EPI == 3) { if (gn < 256) v = fmaxf(v + bias[gn], 0.f); }
                if (OUT_BF16) {
                    ((unsigned short*)Cout)[(size_t)gm * ldc + coff + gn] = f2bf(v);
                } else {
                    if (gm < M)
                        ((float*)Cout)[(size_t)gm * ldc + coff + gn] = v;
                }
            }
        }
    }
}

// ---------------- setup: weights transpose-convert + X convert + rowptr zero --
// warena rows: [0,256)=mw1^T, [256,512)=W1^T, [512,640)=mw2^T, [640,768)=W2^T
__global__ __launch_bounds__(256)
void setup_kernel(const float* __restrict__ X,
                  const float* __restrict__ mw1, const float* __restrict__ W1,
                  const float* __restrict__ mw2, const float* __restrict__ W2,
                  unsigned short* __restrict__ warena, unsigned short* __restrict__ Xb,
                  int* __restrict__ rowptr, int n1, int N, int Mp)
{
    const int b = blockIdx.x, tid = threadIdx.x;
    if (b < 768) {
        const int i = b * 256 + tid;
        if (i < n1) rowptr[i] = 0;
        const int r = i >> 8, k = i & 255;
        float v;
        if (r < 256)      v = mw1[k * 256 + r];
        else if (r < 512) v = W1[k * 256 + (r - 256)];
        else if (r < 640) v = mw2[k * 128 + (r - 512)];
        else              v = W2[k * 128 + (r - 640)];
        warena[i] = f2bf(v);
    } else {
        const int j = (b - 768) * 256 + tid;        // 8 fp32 elems per thread
        if (j >= Mp * 32) return;
        const size_t base = (size_t)j * 8;
        const int row = (int)(base >> 8);
        uint4 o;
        if (row < N) {
            const float4 a = *(const float4*)&X[base];
            const float4 c = *(const float4*)&X[base + 4];
            o.x = pack2(a.x, a.y); o.y = pack2(a.z, a.w);
            o.z = pack2(c.x, c.y); o.w = pack2(c.z, c.w);
        } else {
            o = make_uint4(0, 0, 0, 0);
        }
        *(uint4*)&Xb[base] = o;
    }
}

// ---------------- CSR build ---------------------------------------------------
__global__ __launch_bounds__(256)
void hist_kernel(const int* __restrict__ dst, int* __restrict__ cnt, int E)
{
    int e = blockIdx.x * 256 + threadIdx.x;
    if (e < E) atomicAdd(&cnt[dst[e]], 1);
}

__global__ __launch_bounds__(256)
void reduce_chunks(const int* __restrict__ cnt, int* __restrict__ bsum, int n)
{
    __shared__ int s[256];
    int i = blockIdx.x * 256 + threadIdx.x;
    s[threadIdx.x] = (i < n) ? cnt[i] : 0;
    __syncthreads();
    for (int o = 128; o > 0; o >>= 1) {
        if (threadIdx.x < o) s[threadIdx.x] += s[threadIdx.x + o];
        __syncthreads();
    }
    if (threadIdx.x == 0) bsum[blockIdx.x] = s[0];
}

__global__ __launch_bounds__(256)
void scan_bsum(int* __restrict__ bsum, int nb, int* __restrict__ rowptr, int n)
{
    __shared__ int s[256];
    int t = threadIdx.x;
    int v = (t < nb) ? bsum[t] : 0;
    s[t] = v;
    __syncthreads();
    for (int o = 1; o < 256; o <<= 1) {
        int u = (t >= o) ? s[t - o] : 0;
        __syncthreads();
        s[t] += u;
        __syncthreads();
    }
    if (t < nb) bsum[t] = s[t] - v;
    if (t == 255) rowptr[n] = s[255];
}

__global__ __launch_bounds__(256)
void scan_write(const int* cnt, const int* __restrict__ bsum,
                int* rowptr, int* __restrict__ pos, int n)
{
    __shared__ int s[256];
    int t = threadIdx.x;
    int i = blockIdx.x * 256 + t;
    int v = (i < n) ? cnt[i] : 0;
    s[t] = v;
    __syncthreads();
    for (int o = 1; o < 256; o <<= 1) {
        int u = (t >= o) ? s[t - o] : 0;
        __syncthreads();
        s[t] += u;
        __syncthreads();
    }
    if (i < n) {
        int ex = bsum[blockIdx.x] + s[t] - v;
        rowptr[i] = ex;
        pos[i] = ex;
    }
}

__global__ __launch_bounds__(256)
void scatter_kernel(const int* __restrict__ src, const int* __restrict__ dst,
                    const float* __restrict__ w, int* __restrict__ pos,
                    int2* __restrict__ packed, int E)
{
    int e = blockIdx.x * 256 + threadIdx.x;
    if (e >= E) return;
    int p = atomicAdd(&pos[dst[e]], 1);
    packed[p] = make_int2(src[e], __float_as_int(w[e]));
}

// ---------------- gather SpMM over bf16 rows, 4-way edge unroll ---------------
// x row stride ldx shorts; TPR lanes/row, 8 feats/lane. fp32 out slice (ldo,coff);
// optional bf16 copy at stride ldd (coffd shorts).
template<int TPR, bool RELU, bool DUAL>
__global__ __launch_bounds__(256)
void spmm_csr_bf16(const unsigned short* __restrict__ x,
                   const int* __restrict__ rowptr, const int2* __restrict__ packed,
                   float* __restrict__ outf, unsigned short* __restrict__ outb,
                   int N, int ldx, int ldo, int coff, int ldd)
{
    const int rpb = 256 / TPR;
    const int r = blockIdx.x * rpb + threadIdx.x / TPR;
    const int lane = threadIdx.x % TPR;
    if (r >= N) return;
    const int beg = rowptr[r], end = rowptr[r + 1];
    const unsigned short* xp = x + lane * 8;
    float a0[8] = {0, 0, 0, 0, 0, 0, 0, 0};
    float a1[8] = {0, 0, 0, 0, 0, 0, 0, 0};
    int i = beg;
    for (; i + 3 < end; i += 4) {
        int2 e0 = packed[i], e1 = packed[i + 1], e2 = packed[i + 2], e3 = packed[i + 3];
        uint4 v0 = *(const uint4*)&xp[(size_t)e0.x * ldx];
        uint4 v1 = *(const uint4*)&xp[(size_t)e1.x * ldx];
        uint4 v2 = *(const uint4*)&xp[(size_t)e2.x * ldx];
        uint4 v3 = *(const uint4*)&xp[(size_t)e3.x * ldx];
        float w0 = __int_as_float(e0.y), w1 = __int_as_float(e1.y);
        float w2 = __int_as_float(e2.y), w3 = __int_as_float(e3.y);
        unsigned int s0[4] = {v0.x, v0.y, v0.z, v0.w};
        unsigned int s1[4] = {v1.x, v1.y, v1.z, v1.w};
        unsigned int s2[4] = {v2.x, v2.y, v2.z, v2.w};
        unsigned int s3[4] = {v3.x, v3.y, v3.z, v3.w};
#pragma unroll
        for (int j = 0; j < 4; ++j) {
            a0[2 * j]     = fmaf(w0, __uint_as_float(s0[j] << 16),         a0[2 * j]);
            a0[2 * j + 1] = fmaf(w0, __uint_as_float(s0[j] & 0xFFFF0000u), a0[2 * j + 1]);
            a1[2 * j]     = fmaf(w1, __uint_as_float(s1[j] << 16),         a1[2 * j]);
            a1[2 * j + 1] = fmaf(w1, __uint_as_float(s1[j] & 0xFFFF0000u), a1[2 * j + 1]);
            a0[2 * j]     = fmaf(w2, __uint_as_float(s2[j] << 16),         a0[2 * j]);
            a0[2 * j + 1] = fmaf(w2, __uint_as_float(s2[j] & 0xFFFF0000u), a0[2 * j + 1]);
            a1[2 * j]     = fmaf(w3, __uint_as_float(s3[j] << 16),         a1[2 * j]);
            a1[2 * j + 1] = fmaf(w3, __uint_as_float(s3[j] & 0xFFFF0000u), a1[2 * j + 1]);
        }
    }
    for (; i < end; ++i) {
        int2 e0 = packed[i];
        uint4 v0 = *(const uint4*)&xp[(size_t)e0.x * ldx];
        float w0 = __int_as_float(e0.y);
        unsigned int s0[4] = {v0.x, v0.y, v0.z, v0.w};
#pragma unroll
        for (int j = 0; j < 4; ++j) {
            a0[2 * j]     = fmaf(w0, __uint_as_float(s0[j] << 16),         a0[2 * j]);
            a0[2 * j + 1] = fmaf(w0, __uint_as_float(s0[j] & 0xFFFF0000u), a0[2 * j + 1]);
        }
    }
    float acc[8];
#pragma unroll
    for (int j = 0; j < 8; ++j) {
        acc[j] = a0[j] + a1[j];
        if (RELU) acc[j] = fmaxf(acc[j], 0.f);
    }
    float* o = &outf[(size_t)r * ldo + coff + lane * 8];
    *(float4*)o       = make_float4(acc[0], acc[1], acc[2], acc[3]);
    *(float4*)(o + 4) = make_float4(acc[4], acc[5], acc[6], acc[7]);
    if (DUAL) {
        uint4 p;
        p.x = pack2(acc[0], acc[1]); p.y = pack2(acc[2], acc[3]);
        p.z = pack2(acc[4], acc[5]); p.w = pack2(acc[6], acc[7]);
        *(uint4*)&outb[(size_t)r * ldd + lane * 8] = p;
    }
}

// ---------------- launch ------------------------------------------------------
extern "C" void kernel_launch(void* const* d_in, const int* in_sizes, int n_in,
                              void* d_out, int out_size, void* d_ws, size_t ws_size,
                              hipStream_t stream)
{
    const float* X    = (const float*)d_in[0];
    const int*   esrc = (const int*)  d_in[1];
    const int*   edst = (const int*)  d_in[2];
    const float* ew   = (const float*)d_in[3];
    const float* W1   = (const float*)d_in[4];
    const float* W2   = (const float*)d_in[5];
    const float* mw1  = (const float*)d_in[6];
    const float* mb1  = (const float*)d_in[7];
    const float* mw2  = (const float*)d_in[8];
    const float* mb2  = (const float*)d_in[9];

    const int IN_F = 256, HID_F = 256, OUT_F = 128;
    const int N  = in_sizes[0] / IN_F;
    const int E  = in_sizes[1];
    const int LD = OUT_F + HID_F + OUT_F;       // 512
    const int Mp = (N + 127) & ~127;

    float* out = (float*)d_out;

    // workspace (shorts). Aliasing plan:
    //   arena [Mp][512]: gemmA writes S1(cols 0..255)|Y1(256..511).
    //     K2 reads S1; spmm1 reads Y1 and overwrites cols 0..255 with h1b (S1 dead).
    //     K4 reads h1b from cols 0..255.
    //   XbGb [Mp][256]: Xb (setup->gemmA), then gb [Mp][128] (K4->spmm2; Xb dead).
    unsigned short* arena = (unsigned short*)d_ws;          // [Mp][512]
    unsigned short* XbGb  = arena + (size_t)Mp * 512;       // [Mp][256]
    unsigned short* warena = XbGb + (size_t)Mp * 256;       // [768][256]
    unsigned short* Wc   = warena;                          // [512][256] = [mw1^T; W1^T]
    unsigned short* mw2t = warena + 512 * 256;              // [128][256]
    unsigned short* w2t  = warena + 640 * 256;              // [128][256]
    int* rowptr = (int*)(warena + 768 * 256);               // N+1
    int* bsum   = rowptr + (((N + 1) + 3) & ~3);            // 256
    int* pos    = bsum + 256;                               // N
    int2* packed = (int2*)(pos + ((N + 1) & ~1));           // E

    dim3 blk(256);
    const int nb = (N + 255) / 256;
    const int mT = Mp / 128;
    const int mTp = (mT + 7) & ~7;              // swizzle groups of 8 mtiles

    // setup: weight conversion + rowptr zero + X->bf16
    setup_kernel<<<768 + (Mp * 32 + 255) / 256, blk, 0, stream>>>(
        X, mw1, W1, mw2, W2, warena, XbGb, rowptr, N + 1, N, Mp);

    // CSR build
    hist_kernel<<<(E + 255) / 256, blk, 0, stream>>>(edst, rowptr, E);
    reduce_chunks<<<nb, blk, 0, stream>>>(rowptr, bsum, N);
    scan_bsum<<<1, blk, 0, stream>>>(bsum, nb, rowptr, N);
    scan_write<<<nb, blk, 0, stream>>>(rowptr, bsum, rowptr, pos, N);
    scatter_kernel<<<(E + 255) / 256, blk, 0, stream>>>(esrc, edst, ew, pos, packed, E);

    // gemmA: arena = Xb @ [mw1 | W1] (relu+b1 on cols<256) -> bf16, XCD-swizzled
    gemm_mfma<true, 3, true><<<mTp * 4, blk, 0, stream>>>(
        XbGb, Wc, mb1, arena, N, mT, 256, 512, 0);

    // K2: out[:,0:128] = S1 @ mw2 + b2 (fp32)
    gemm_mfma<false, 2, false><<<dim3(mT, 1), blk, 0, stream>>>(
        arena, mw2t, mb2, out, N, mT, 512, LD, 0);

    // SpMM1: h1 = relu(A @ Y1) -> out[:,128:384] fp32 + h1b bf16 (arena cols 0..255)
    spmm_csr_bf16<32, true, true><<<(N + 7) / 8, blk, 0, stream>>>(
        arena + 256, rowptr, packed, out, arena, N, 512, LD, OUT_F, 512);

    // K4: gb = h1b @ W2 (bf16) -> XbGb (Xb dead)
    gemm_mfma<true, 0, false><<<dim3(mT, 1), blk, 0, stream>>>(
        arena, w2t, nullptr, XbGb, N, mT, 512, 128, 0);

    // SpMM2: out[:,384:512] = A @ g (fp32)
    spmm_csr_bf16<16, false, false><<<(N + 15) / 16, blk, 0, stream>>>(
        XbGb, rowptr, packed, out, nullptr, N, 128, LD, OUT_F + HID_F, 0);
}